// Round 3
// baseline (555.715 us; speedup 1.0000x reference)
//
#include <hip/hip_runtime.h>

typedef unsigned int uint;
typedef unsigned short ushort;
typedef __attribute__((ext_vector_type(8))) short bfrag_t;
typedef __attribute__((ext_vector_type(4))) short s4_t;
typedef __attribute__((ext_vector_type(4))) float f4_t;

#define EPSV 1e-5f

__device__ __forceinline__ float4 ld4(const float* p) { return *(const float4*)p; }
__device__ __forceinline__ void st4(float* p, float4 v) { *(float4*)p = v; }

__device__ __forceinline__ ushort f2bf(float f) {
    union { float f; uint u; } v; v.f = f;
    uint r = v.u + 0x7fffu + ((v.u >> 16) & 1u);
    return (ushort)(r >> 16);
}
__device__ __forceinline__ float bf2f(ushort s) {
    union { uint u; float f; } v; v.u = ((uint)s) << 16;
    return v.f;
}
__device__ __forceinline__ float bfhi(uint u) { union { uint u; float f; } v; v.u = u & 0xffff0000u; return v.f; }
__device__ __forceinline__ float bflo(uint u) { union { uint u; float f; } v; v.u = u << 16; return v.f; }
__device__ __forceinline__ uint pk2(float a, float b) { return (uint)f2bf(a) | ((uint)f2bf(b) << 16); }

union FragU { uint u[4]; bfrag_t v; };

// wT[(k*256+co)*256+ci] = bf16(w[co][ci][k])
__global__ __launch_bounds__(256) void prep_wdef_bf16(const float* __restrict__ w1, const float* __restrict__ w2,
                                                      ushort* __restrict__ o1, ushort* __restrict__ o2) {
    int idx = blockIdx.x * 256 + threadIdx.x;           // 2*589824
    int sel = idx >= 589824;
    int i = sel ? idx - 589824 : idx;
    const float* w = sel ? w2 : w1;
    ushort* o = sel ? o2 : o1;
    int ci = i & 255, co = (i >> 8) & 255, k = i >> 16;
    o[i] = f2bf(w[(((co << 8) + ci) * 9) + k]);
}

// wO[(k*32+co)*256+ci] = co<18 ? bf16(w[co][ci][k]) : 0
__global__ __launch_bounds__(256) void prep_woff_bf16(const float* __restrict__ w1, const float* __restrict__ w2,
                                                      ushort* __restrict__ o1, ushort* __restrict__ o2) {
    int idx = blockIdx.x * 256 + threadIdx.x;           // 2*73728
    int sel = idx >= 73728;
    int i = sel ? idx - 73728 : idx;
    const float* w = sel ? w2 : w1;
    ushort* o = sel ? o2 : o1;
    int ci = i & 255, co = (i >> 8) & 31, k = i >> 13;
    o[i] = (co < 18) ? f2bf(w[(((co << 8) + ci) * 9) + k]) : (ushort)0;
}

// NCHW fp32 -> NHWC bf16
__global__ __launch_bounds__(256) void transpose_to_nhwc_bf16(const float* __restrict__ in, ushort* __restrict__ out) {
    __shared__ float lds[64][65];
    int bid = blockIdx.x;                 // b*256 + y*4 + cb
    int cb = bid & 3, y = (bid >> 2) & 63, b = bid >> 8;
    int c0 = cb << 6;
    int tid = threadIdx.x;
#pragma unroll
    for (int i = 0; i < 4; ++i) {
        int q = tid + (i << 8);
        int c_l = q >> 4, x4 = (q & 15) << 2;
        float4 v = ld4(&in[((b * 256 + c0 + c_l) << 12) + (y << 6) + x4]);
        lds[c_l][x4 + 0] = v.x; lds[c_l][x4 + 1] = v.y; lds[c_l][x4 + 2] = v.z; lds[c_l][x4 + 3] = v.w;
    }
    __syncthreads();
#pragma unroll
    for (int i = 0; i < 4; ++i) {
        int q = tid + (i << 8);
        int x_l = q >> 4, c4 = (q & 15) << 2;
        s4_t v;
        v.x = (short)f2bf(lds[c4 + 0][x_l]); v.y = (short)f2bf(lds[c4 + 1][x_l]);
        v.z = (short)f2bf(lds[c4 + 2][x_l]); v.w = (short)f2bf(lds[c4 + 3][x_l]);
        *(s4_t*)&out[(((b << 12) + (y << 6) + x_l) << 8) + c0 + c4] = v;
    }
}

// Offset conv: one wave per 16-px tile, full 32 (18 used) co. No LDS, no barriers.
__global__ __launch_bounds__(64, 4) void offconv_reg(const ushort* __restrict__ xb, const ushort* __restrict__ wO,
                                                     const float* __restrict__ bias, float* __restrict__ offb) {
    int bidx = blockIdx.x;                 // 1024
    int tile = (bidx & 7) * 128 + (bidx >> 3);   // XCD-local px clustering
    int px0 = tile << 4;
    int lane = threadIdx.x;
    int lr = lane & 15, lq = lane >> 4;
    int pxl = px0 + lr;
    int b = pxl >> 12, y = (pxl >> 6) & 63, x = pxl & 63;

    f4_t acc0 = (f4_t){0.f,0.f,0.f,0.f}, acc1 = (f4_t){0.f,0.f,0.f,0.f};
#pragma unroll
    for (int tap = 0; tap < 9; ++tap) {
        int ky = tap / 3, kx = tap - ky * 3;
        int yy = y + ky - 1, xx = x + kx - 1;
        bool valid = (yy >= 0) && (yy < 64) && (xx >= 0) && (xx < 64);
        const ushort* arow = xb + ((((b << 6) + yy) << 6) + xx) * 256;
        const ushort* wrow = wO + ((tap << 5) << 8);
#pragma unroll
        for (int s = 0; s < 8; ++s) {
            int cio = (s << 5) + (lq << 3);
            bfrag_t afr = (bfrag_t){0,0,0,0,0,0,0,0};
            if (valid) afr = *(const bfrag_t*)(arow + cio);
            bfrag_t b0 = *(const bfrag_t*)(wrow + (lr << 8) + cio);
            bfrag_t b1 = *(const bfrag_t*)(wrow + ((16 + lr) << 8) + cio);
            acc0 = __builtin_amdgcn_mfma_f32_16x16x32_bf16(afr, b0, acc0, 0, 0, 0);
            acc1 = __builtin_amdgcn_mfma_f32_16x16x32_bf16(afr, b1, acc1, 0, 0, 0);
        }
    }
    // C layout: row = lq*4+r (px), col = lr (co)
#pragma unroll
    for (int r = 0; r < 4; ++r) {
        int row = (px0 + (lq << 2) + r) * 18;
        if (lr < 18) offb[row + lr] = acc0[r] + bias[lr];
        if (lr < 2)  offb[row + 16 + lr] = acc1[r] + bias[16 + lr];
    }
}

// Deformable conv: one wave per (16-px tile, 128-co half). All-register, no LDS/barriers.
__global__ __launch_bounds__(64, 4) void deform_reg(const ushort* __restrict__ xb, const float* __restrict__ offb,
                                                    const ushort* __restrict__ wT, ushort* __restrict__ outb) {
    int bidx = blockIdx.x;                 // 2048
    int slot = bidx >> 3;                  // 0..255
    int tile = (bidx & 7) * 128 + (slot >> 1);
    int coH = slot & 1;
    int px0 = tile << 4;
    int nb0 = coH << 7;
    int lane = threadIdx.x;
    int lr = lane & 15, lq = lane >> 4;
    int pxl = px0 + lr;
    int b = pxl >> 12, y = (pxl >> 6) & 63, x = pxl & 63;
    int base = b << 12;

    // prefetch all 9 (dy,dx) pairs for this lane's pixel (72B row, 8B aligned)
    float2 off[9];
#pragma unroll
    for (int t = 0; t < 9; ++t) off[t] = *(const float2*)(offb + pxl * 18 + 2 * t);

    f4_t acc[8];
#pragma unroll
    for (int nt = 0; nt < 8; ++nt) acc[nt] = (f4_t){0.f,0.f,0.f,0.f};

#pragma unroll
    for (int tap = 0; tap < 9; ++tap) {
        int ky = tap / 3, kx = tap - ky * 3;
        float py = off[tap].x + (float)(y - 1 + ky);
        float pxx = off[tap].y + (float)(x - 1 + kx);
        float y0f = floorf(py), x0f = floorf(pxx);
        float ly = py - y0f, lx = pxx - x0f;
        int y0 = (int)y0f, x0 = (int)x0f;
        int y1 = y0 + 1, x1 = x0 + 1;
        bool vy0 = (y0 >= 0) && (y0 < 64), vy1 = (y1 >= 0) && (y1 < 64);
        bool vx0 = (x0 >= 0) && (x0 < 64), vx1 = (x1 >= 0) && (x1 < 64);
        int i0 = (vy0 && vx0) ? ((base + (y0 << 6) + x0) << 8) : -1;
        int i1 = (vy0 && vx1) ? ((base + (y0 << 6) + x1) << 8) : -1;
        int i2 = (vy1 && vx0) ? ((base + (y1 << 6) + x0) << 8) : -1;
        int i3 = (vy1 && vx1) ? ((base + (y1 << 6) + x1) << 8) : -1;
        float w0 = (1.f - ly) * (1.f - lx);
        float w1 = (1.f - ly) * lx;
        float w2 = ly * (1.f - lx);
        float w3 = ly * lx;
        const ushort* wk = wT + (((tap << 8) + nb0) << 8);
#pragma unroll
        for (int s = 0; s < 8; ++s) {
            int cio = (s << 5) + (lq << 3);
            float f0 = 0.f, f1 = 0.f, f2 = 0.f, f3 = 0.f, f4 = 0.f, f5 = 0.f, f6 = 0.f, f7 = 0.f;
#define CORNER(ii, ww) if (ii >= 0) { \
                uint4 q = *(const uint4*)(xb + ii + cio); \
                f0 += ww * bflo(q.x); f1 += ww * bfhi(q.x); \
                f2 += ww * bflo(q.y); f3 += ww * bfhi(q.y); \
                f4 += ww * bflo(q.z); f5 += ww * bfhi(q.z); \
                f6 += ww * bflo(q.w); f7 += ww * bfhi(q.w); }
            CORNER(i0, w0) CORNER(i1, w1) CORNER(i2, w2) CORNER(i3, w3)
#undef CORNER
            FragU au;
            au.u[0] = pk2(f0, f1); au.u[1] = pk2(f2, f3);
            au.u[2] = pk2(f4, f5); au.u[3] = pk2(f6, f7);
            bfrag_t afr = au.v;
#pragma unroll
            for (int ntg = 0; ntg < 2; ++ntg) {
                bfrag_t bf[4];
#pragma unroll
                for (int j = 0; j < 4; ++j) {
                    int co = nb0 + (((ntg << 2) + j) << 4) + lr;
                    bf[j] = *(const bfrag_t*)(wT + (((tap << 8) + co) << 8) + cio);
                }
#pragma unroll
                for (int j = 0; j < 4; ++j)
                    acc[(ntg << 2) + j] = __builtin_amdgcn_mfma_f32_16x16x32_bf16(afr, bf[j], acc[(ntg << 2) + j], 0, 0, 0);
            }
        }
        (void)wk;
    }
#pragma unroll
    for (int nt = 0; nt < 8; ++nt) {
        int co = nb0 + (nt << 4) + lr;
#pragma unroll
        for (int r = 0; r < 4; ++r) {
            int row = px0 + (lq << 2) + r;
            outb[(row << 8) + co] = f2bf(acc[nt][r]);
        }
    }
}

// GroupNorm stats over bf16 NHWC: per (b,g) mean & rstd
__global__ __launch_bounds__(256) void gn_stats_bf(const ushort* __restrict__ p0, float* __restrict__ stats) {
    int bid = blockIdx.x;     // b*32+g
    int b = bid >> 5, g = bid & 31;
    const ushort* p = p0 + (b << 20) + (g << 3);
    float s = 0.f, s2 = 0.f;
    for (int px = threadIdx.x; px < 4096; px += 256) {
        uint4 q = *(const uint4*)(p + (px << 8));
        float v0 = bflo(q.x), v1 = bfhi(q.x), v2 = bflo(q.y), v3 = bfhi(q.y);
        float v4 = bflo(q.z), v5 = bfhi(q.z), v6 = bflo(q.w), v7 = bfhi(q.w);
        s += v0 + v1 + v2 + v3 + v4 + v5 + v6 + v7;
        s2 += v0 * v0 + v1 * v1 + v2 * v2 + v3 * v3 + v4 * v4 + v5 * v5 + v6 * v6 + v7 * v7;
    }
#pragma unroll
    for (int o = 32; o > 0; o >>= 1) { s += __shfl_down(s, o, 64); s2 += __shfl_down(s2, o, 64); }
    __shared__ float ws1[4], ws2[4];
    int wv = threadIdx.x >> 6, lane = threadIdx.x & 63;
    if (lane == 0) { ws1[wv] = s; ws2[wv] = s2; }
    __syncthreads();
    if (threadIdx.x == 0) {
        float t1 = ws1[0] + ws1[1] + ws1[2] + ws1[3];
        float t2 = ws2[0] + ws2[1] + ws2[2] + ws2[3];
        float mean = t1 * (1.f / 32768.f);
        float var = t2 * (1.f / 32768.f) - mean * mean;
        stats[bid * 2] = mean;
        stats[bid * 2 + 1] = rsqrtf(var + EPSV);
    }
}

// GN + ReLU, bf16 NHWC -> bf16 NHWC (8 ch per thread)
__global__ __launch_bounds__(256) void gn_apply_relu_bb(const ushort* __restrict__ in, const float* __restrict__ stats,
                                                        const float* __restrict__ gamma, const float* __restrict__ beta,
                                                        ushort* __restrict__ outb) {
    int q = blockIdx.x * 256 + threadIdx.x;   // 524288
    int e0 = q << 3;
    int c0 = e0 & 255;
    int b = e0 >> 20;
    int g = c0 >> 3;
    float mean = stats[((b << 5) + g) * 2];
    float rstd = stats[((b << 5) + g) * 2 + 1];
    uint4 v = *(const uint4*)(in + e0);
    float4 ga0 = ld4(&gamma[c0]), ga1 = ld4(&gamma[c0 + 4]);
    float4 be0 = ld4(&beta[c0]),  be1 = ld4(&beta[c0 + 4]);
    uint4 o;
    o.x = pk2(fmaxf((bflo(v.x) - mean) * rstd * ga0.x + be0.x, 0.f),
              fmaxf((bfhi(v.x) - mean) * rstd * ga0.y + be0.y, 0.f));
    o.y = pk2(fmaxf((bflo(v.y) - mean) * rstd * ga0.z + be0.z, 0.f),
              fmaxf((bfhi(v.y) - mean) * rstd * ga0.w + be0.w, 0.f));
    o.z = pk2(fmaxf((bflo(v.z) - mean) * rstd * ga1.x + be1.x, 0.f),
              fmaxf((bfhi(v.z) - mean) * rstd * ga1.y + be1.y, 0.f));
    o.w = pk2(fmaxf((bflo(v.z + 0) - mean) * 0.f + fmaxf((bflo(v.w) - mean) * rstd * ga1.z + be1.z, 0.f), 0.f),
              fmaxf((bfhi(v.w) - mean) * rstd * ga1.w + be1.w, 0.f));
    // fix o.w low half (written confusingly above): recompute cleanly
    o.w = pk2(fmaxf((bflo(v.w) - mean) * rstd * ga1.z + be1.z, 0.f),
              fmaxf((bfhi(v.w) - mean) * rstd * ga1.w + be1.w, 0.f));
    *(uint4*)&outb[e0] = o;
}

// NHWC bf16 -> NCHW with fused GN2 + residual + ReLU
__global__ __launch_bounds__(256) void final_bf16(const ushort* __restrict__ v2, const float* __restrict__ stats,
                                                  const float* __restrict__ gamma, const float* __restrict__ beta,
                                                  const float* __restrict__ xin, float* __restrict__ out) {
    __shared__ float lds[64][65];
    int bid = blockIdx.x;
    int cb = bid & 3, y = (bid >> 2) & 63, b = bid >> 8;
    int c0 = cb << 6;
    int tid = threadIdx.x;
#pragma unroll
    for (int i = 0; i < 4; ++i) {
        int q = tid + (i << 8);
        int x_l = q >> 4, c4 = (q & 15) << 2;
        s4_t v = *(const s4_t*)&v2[(((b << 12) + (y << 6) + x_l) << 8) + c0 + c4];
        lds[c4 + 0][x_l] = bf2f((ushort)v.x); lds[c4 + 1][x_l] = bf2f((ushort)v.y);
        lds[c4 + 2][x_l] = bf2f((ushort)v.z); lds[c4 + 3][x_l] = bf2f((ushort)v.w);
    }
    __syncthreads();
#pragma unroll
    for (int i = 0; i < 4; ++i) {
        int q = tid + (i << 8);
        int c_l = q >> 4, x4 = (q & 15) << 2;
        int c = c0 + c_l;
        int g = c >> 3;
        float mean = stats[((b << 5) + g) * 2];
        float rstd = stats[((b << 5) + g) * 2 + 1];
        float ga = gamma[c], be = beta[c];
        const float* xp = &xin[((b << 8) + c) * 4096 + (y << 6) + x4];
        float4 r = ld4(xp);
        float4 o;
        o.x = fmaxf((lds[c_l][x4 + 0] - mean) * rstd * ga + be + r.x, 0.f);
        o.y = fmaxf((lds[c_l][x4 + 1] - mean) * rstd * ga + be + r.y, 0.f);
        o.z = fmaxf((lds[c_l][x4 + 2] - mean) * rstd * ga + be + r.z, 0.f);
        o.w = fmaxf((lds[c_l][x4 + 3] - mean) * rstd * ga + be + r.w, 0.f);
        st4(&out[((b << 8) + c) * 4096 + (y << 6) + x4], o);
    }
}

extern "C" void kernel_launch(void* const* d_in, const int* in_sizes, int n_in,
                              void* d_out, int out_size, void* d_ws, size_t ws_size,
                              hipStream_t stream) {
    (void)in_sizes; (void)n_in; (void)out_size; (void)ws_size;
    const float* x      = (const float*)d_in[0];
    const float* w_off1 = (const float*)d_in[1];
    const float* b_off1 = (const float*)d_in[2];
    const float* w_off2 = (const float*)d_in[3];
    const float* b_off2 = (const float*)d_in[4];
    const float* w_def1 = (const float*)d_in[5];
    const float* w_def2 = (const float*)d_in[6];
    const float* gamma1 = (const float*)d_in[7];
    const float* beta1  = (const float*)d_in[8];
    const float* gamma2 = (const float*)d_in[9];
    const float* beta2  = (const float*)d_in[10];
    float* out = (float*)d_out;

    float* ws = (float*)d_ws;
    float*  xb_f   = ws;                      // 2,097,152 floats: xb (stage1) / v2b (stage2)
    float*  xb2_f  = xb_f + 2097152;          // 2,097,152: xb2 bf16
    float*  wT1_f  = xb2_f + 2097152;         // 294,912
    float*  wT2_f  = wT1_f + 294912;          // 294,912
    float*  wO1_f  = wT2_f + 294912;          // 36,864
    float*  wO2_f  = wO1_f + 36864;           // 36,864
    float*  offb   = wO2_f + 36864;           // 294,912 (16384 x 18)
    float*  stats1 = offb + 294912;           // 256
    float*  stats2 = stats1 + 256;            // 256

    ushort* xb  = (ushort*)xb_f;
    ushort* v2b = (ushort*)xb_f;              // reuses xb slot in stage 2
    ushort* xb2 = (ushort*)xb2_f;
    ushort* wT1 = (ushort*)wT1_f;
    ushort* wT2 = (ushort*)wT2_f;
    ushort* wO1 = (ushort*)wO1_f;
    ushort* wO2 = (ushort*)wO2_f;
    ushort* t1b = (ushort*)d_out;             // stage-1 deform out (bf16) parked in d_out

    prep_wdef_bf16<<<4608, 256, 0, stream>>>(w_def1, w_def2, wT1, wT2);
    prep_woff_bf16<<<576, 256, 0, stream>>>(w_off1, w_off2, wO1, wO2);
    transpose_to_nhwc_bf16<<<1024, 256, 0, stream>>>(x, xb);

    offconv_reg<<<1024, 64, 0, stream>>>(xb, wO1, b_off1, offb);
    deform_reg<<<2048, 64, 0, stream>>>(xb, offb, wT1, t1b);
    gn_stats_bf<<<128, 256, 0, stream>>>(t1b, stats1);
    gn_apply_relu_bb<<<2048, 256, 0, stream>>>(t1b, stats1, gamma1, beta1, xb2);

    offconv_reg<<<1024, 64, 0, stream>>>(xb2, wO2, b_off2, offb);
    deform_reg<<<2048, 64, 0, stream>>>(xb2, offb, wT2, v2b);
    gn_stats_bf<<<128, 256, 0, stream>>>(v2b, stats2);
    final_bf16<<<1024, 256, 0, stream>>>(v2b, stats2, gamma2, beta2, x, out);
}

// Round 5
// 339.298 us; speedup vs baseline: 1.6378x; 1.6378x over previous
//
#include <hip/hip_runtime.h>

typedef unsigned int uint;
typedef unsigned short ushort;
typedef __attribute__((ext_vector_type(8))) short bfrag_t;
typedef __attribute__((ext_vector_type(4))) short s4_t;
typedef __attribute__((ext_vector_type(4))) float f4_t;

#define EPSV 1e-5f

__device__ __forceinline__ float4 ld4(const float* p) { return *(const float4*)p; }
__device__ __forceinline__ void st4(float* p, float4 v) { *(float4*)p = v; }

__device__ __forceinline__ ushort f2bf(float f) {
    union { float f; uint u; } v; v.f = f;
    uint r = v.u + 0x7fffu + ((v.u >> 16) & 1u);
    return (ushort)(r >> 16);
}
__device__ __forceinline__ float bf2f(ushort s) {
    union { uint u; float f; } v; v.u = ((uint)s) << 16;
    return v.f;
}
__device__ __forceinline__ float bfhi(uint u) { union { uint u; float f; } v; v.u = u & 0xffff0000u; return v.f; }
__device__ __forceinline__ float bflo(uint u) { union { uint u; float f; } v; v.u = u << 16; return v.f; }
__device__ __forceinline__ uint pk2(float a, float b) { return (uint)f2bf(a) | ((uint)f2bf(b) << 16); }

// wT[(k*256+co)*256+ci] = bf16(w[co][ci][k])
__global__ __launch_bounds__(256) void prep_wdef_bf16(const float* __restrict__ w1, const float* __restrict__ w2,
                                                      ushort* __restrict__ o1, ushort* __restrict__ o2) {
    int idx = blockIdx.x * 256 + threadIdx.x;           // 2*589824
    int sel = idx >= 589824;
    int i = sel ? idx - 589824 : idx;
    const float* w = sel ? w2 : w1;
    ushort* o = sel ? o2 : o1;
    int ci = i & 255, co = (i >> 8) & 255, k = i >> 16;
    o[i] = f2bf(w[(((co << 8) + ci) * 9) + k]);
}

// wO[(k*32+co)*256+ci] = co<18 ? bf16(w[co][ci][k]) : 0
__global__ __launch_bounds__(256) void prep_woff_bf16(const float* __restrict__ w1, const float* __restrict__ w2,
                                                      ushort* __restrict__ o1, ushort* __restrict__ o2) {
    int idx = blockIdx.x * 256 + threadIdx.x;           // 2*73728
    int sel = idx >= 73728;
    int i = sel ? idx - 73728 : idx;
    const float* w = sel ? w2 : w1;
    ushort* o = sel ? o2 : o1;
    int ci = i & 255, co = (i >> 8) & 31, k = i >> 13;
    o[i] = (co < 18) ? f2bf(w[(((co << 8) + ci) * 9) + k]) : (ushort)0;
}

// NCHW fp32 -> NHWC bf16
__global__ __launch_bounds__(256) void transpose_to_nhwc_bf16(const float* __restrict__ in, ushort* __restrict__ out) {
    __shared__ float lds[64][65];
    int bid = blockIdx.x;                 // b*256 + y*4 + cb
    int cb = bid & 3, y = (bid >> 2) & 63, b = bid >> 8;
    int c0 = cb << 6;
    int tid = threadIdx.x;
#pragma unroll
    for (int i = 0; i < 4; ++i) {
        int q = tid + (i << 8);
        int c_l = q >> 4, x4 = (q & 15) << 2;
        float4 v = ld4(&in[((b * 256 + c0 + c_l) << 12) + (y << 6) + x4]);
        lds[c_l][x4 + 0] = v.x; lds[c_l][x4 + 1] = v.y; lds[c_l][x4 + 2] = v.z; lds[c_l][x4 + 3] = v.w;
    }
    __syncthreads();
#pragma unroll
    for (int i = 0; i < 4; ++i) {
        int q = tid + (i << 8);
        int x_l = q >> 4, c4 = (q & 15) << 2;
        s4_t v;
        v.x = (short)f2bf(lds[c4 + 0][x_l]); v.y = (short)f2bf(lds[c4 + 1][x_l]);
        v.z = (short)f2bf(lds[c4 + 2][x_l]); v.w = (short)f2bf(lds[c4 + 3][x_l]);
        *(s4_t*)&out[(((b << 12) + (y << 6) + x_l) << 8) + c0 + c4] = v;
    }
}

// Offset conv: one wave per 16-px tile, 32 (18 used) co. No LDS, no barriers. (unchanged from R3 pass)
__global__ __launch_bounds__(64, 4) void offconv_reg(const ushort* __restrict__ xb, const ushort* __restrict__ wO,
                                                     const float* __restrict__ bias, float* __restrict__ offb) {
    int bidx = blockIdx.x;                 // 1024
    int tile = (bidx & 7) * 128 + (bidx >> 3);   // XCD-local px clustering
    int px0 = tile << 4;
    int lane = threadIdx.x;
    int lr = lane & 15, lq = lane >> 4;
    int pxl = px0 + lr;
    int b = pxl >> 12, y = (pxl >> 6) & 63, x = pxl & 63;

    f4_t acc0 = (f4_t){0.f,0.f,0.f,0.f}, acc1 = (f4_t){0.f,0.f,0.f,0.f};
#pragma unroll
    for (int tap = 0; tap < 9; ++tap) {
        int ky = tap / 3, kx = tap - ky * 3;
        int yy = y + ky - 1, xx = x + kx - 1;
        bool valid = (yy >= 0) && (yy < 64) && (xx >= 0) && (xx < 64);
        const ushort* arow = xb + ((((b << 6) + yy) << 6) + xx) * 256;
        const ushort* wrow = wO + ((tap << 5) << 8);
#pragma unroll
        for (int s = 0; s < 8; ++s) {
            int cio = (s << 5) + (lq << 3);
            bfrag_t afr = (bfrag_t){0,0,0,0,0,0,0,0};
            if (valid) afr = *(const bfrag_t*)(arow + cio);
            bfrag_t b0 = *(const bfrag_t*)(wrow + (lr << 8) + cio);
            bfrag_t b1 = *(const bfrag_t*)(wrow + ((16 + lr) << 8) + cio);
            acc0 = __builtin_amdgcn_mfma_f32_16x16x32_bf16(afr, b0, acc0, 0, 0, 0);
            acc1 = __builtin_amdgcn_mfma_f32_16x16x32_bf16(afr, b1, acc1, 0, 0, 0);
        }
    }
#pragma unroll
    for (int r = 0; r < 4; ++r) {
        int row = (px0 + (lq << 2) + r) * 18;
        if (lr < 18) offb[row + lr] = acc0[r] + bias[lr];
        if (lr < 2)  offb[row + 16 + lr] = acc1[r] + bias[16 + lr];
    }
}

// Deformable conv: block = 64 px x 128 co (co-half), 4 waves, grid 512 (2 blocks/CU).
// Per tap: 2 ci-chunks of 128, double-buffered in 32KB LDS, 18 pipelined steps.
// A-tile k-major: As[buf][kblk(16)][px(64)][8 shorts].
__global__ __launch_bounds__(256, 2) void deform_mfma(const ushort* __restrict__ xb, const float* __restrict__ offb,
                                                      const ushort* __restrict__ wT, ushort* __restrict__ outb) {
    __shared__ short As[2][8192];      // 2 x 16KB

    int bidx = blockIdx.x;             // 512
    int xcd = bidx & 7;
    int j = bidx >> 3;                 // 0..63
    int coH = j & 1;
    int tile = xcd * 32 + (j >> 1);    // 0..255
    int px0 = tile << 6;
    int nb0 = coH << 7;

    int tid = threadIdx.x;
    int wave = tid >> 6, lane = tid & 63;
    int lr = lane & 15, lq = lane >> 4;

    // gather role: 4 threads per pixel, 32 ci each per chunk
    int gpx = tid >> 2;                // 0..63
    int cblk = tid & 3;
    int pxg = px0 + gpx;
    int gy = (pxg >> 6) & 63, gx = pxg & 63;
    int gbase = (pxg >> 12) << 12;

    float2 off[9];
#pragma unroll
    for (int t = 0; t < 9; ++t) off[t] = *(const float2*)(offb + pxg * 18 + 2 * t);

    f4_t acc[4][2];
#pragma unroll
    for (int m = 0; m < 4; ++m) { acc[m][0] = (f4_t){0.f,0.f,0.f,0.f}; acc[m][1] = (f4_t){0.f,0.f,0.f,0.f}; }

    auto gather = [&](int step, int buf) {
        int tap = step >> 1, chunk = step & 1;
        int ky = tap / 3, kx = tap - ky * 3;
        float py  = off[tap].x + (float)(gy - 1 + ky);
        float pxx = off[tap].y + (float)(gx - 1 + kx);
        float y0f = floorf(py), x0f = floorf(pxx);
        float ly = py - y0f, lx = pxx - x0f;
        int y0 = (int)y0f, x0 = (int)x0f;
        int y1 = y0 + 1, x1 = x0 + 1;
        bool vy0 = (y0 >= 0) && (y0 < 64), vy1 = (y1 >= 0) && (y1 < 64);
        bool vx0 = (x0 >= 0) && (x0 < 64), vx1 = (x1 >= 0) && (x1 < 64);
        int i0 = (vy0 && vx0) ? ((gbase + (y0 << 6) + x0) << 8) : -1;
        int i1 = (vy0 && vx1) ? ((gbase + (y0 << 6) + x1) << 8) : -1;
        int i2 = (vy1 && vx0) ? ((gbase + (y1 << 6) + x0) << 8) : -1;
        int i3 = (vy1 && vx1) ? ((gbase + (y1 << 6) + x1) << 8) : -1;
        float w0 = (1.f - ly) * (1.f - lx);
        float w1 = (1.f - ly) * lx;
        float w2 = ly * (1.f - lx);
        float w3 = ly * lx;
        int cibase = (chunk << 7) + (cblk << 5);
#pragma unroll
        for (int u = 0; u < 4; ++u) {
            int cio = cibase + (u << 3);
            uint4 q0 = make_uint4(0,0,0,0), q1 = q0, q2 = q0, q3 = q0;
            if (i0 >= 0) q0 = *(const uint4*)(xb + i0 + cio);
            if (i1 >= 0) q1 = *(const uint4*)(xb + i1 + cio);
            if (i2 >= 0) q2 = *(const uint4*)(xb + i2 + cio);
            if (i3 >= 0) q3 = *(const uint4*)(xb + i3 + cio);
            float f0 = w0*bflo(q0.x) + w1*bflo(q1.x) + w2*bflo(q2.x) + w3*bflo(q3.x);
            float f1 = w0*bfhi(q0.x) + w1*bfhi(q1.x) + w2*bfhi(q2.x) + w3*bfhi(q3.x);
            float f2 = w0*bflo(q0.y) + w1*bflo(q1.y) + w2*bflo(q2.y) + w3*bflo(q3.y);
            float f3 = w0*bfhi(q0.y) + w1*bfhi(q1.y) + w2*bfhi(q2.y) + w3*bfhi(q3.y);
            float f4 = w0*bflo(q0.z) + w1*bflo(q1.z) + w2*bflo(q2.z) + w3*bflo(q3.z);
            float f5 = w0*bfhi(q0.z) + w1*bfhi(q1.z) + w2*bfhi(q2.z) + w3*bfhi(q3.z);
            float f6 = w0*bflo(q0.w) + w1*bflo(q1.w) + w2*bflo(q2.w) + w3*bflo(q3.w);
            float f7 = w0*bfhi(q0.w) + w1*bfhi(q1.w) + w2*bfhi(q2.w) + w3*bfhi(q3.w);
            uint4 o;
            o.x = pk2(f0, f1); o.y = pk2(f2, f3); o.z = pk2(f4, f5); o.w = pk2(f6, f7);
            // kblk_local = cblk*4+u (0..15), layout [kblk][px][8]
            *(uint4*)&As[buf][(((cblk << 2) + u) * 64 + gpx) << 3] = o;
        }
    };

    auto gemm = [&](int step, int buf) {
        int tap = step >> 1, chunk = step & 1;
        const ushort* wrow = wT + (((tap << 8) + nb0 + (wave << 5) + lr) << 8) + (chunk << 7) + (lq << 3);
#pragma unroll
        for (int s = 0; s < 4; ++s) {
            bfrag_t b0 = *(const bfrag_t*)(wrow + (s << 5));
            bfrag_t b1 = *(const bfrag_t*)(wrow + (16 << 8) + (s << 5));
#pragma unroll
            for (int m = 0; m < 4; ++m) {
                const short* ap = &As[buf][((((s << 2) + lq) << 6) + (m << 4) + lr) << 3];
                bfrag_t a = *(const bfrag_t*)ap;
                acc[m][0] = __builtin_amdgcn_mfma_f32_16x16x32_bf16(a, b0, acc[m][0], 0, 0, 0);
                acc[m][1] = __builtin_amdgcn_mfma_f32_16x16x32_bf16(a, b1, acc[m][1], 0, 0, 0);
            }
        }
    };

    gather(0, 0);
    __syncthreads();
    for (int step = 0; step < 18; ++step) {
        if (step < 17) gather(step + 1, (step + 1) & 1);  // fill other buffer (already consumed)
        gemm(step, step & 1);
        __syncthreads();
    }

#pragma unroll
    for (int m = 0; m < 4; ++m) {
        int co = nb0 + (wave << 5) + lr;
#pragma unroll
        for (int r = 0; r < 4; ++r) {
            int row = px0 + (m << 4) + (lq << 2) + r;
            outb[(row << 8) + co] = f2bf(acc[m][0][r]);
            outb[(row << 8) + co + 16] = f2bf(acc[m][1][r]);
        }
    }
}

// GN partial sums: grid 512 = b(4) x chunk(128); block reads 32 px x 256 ch contiguous.
__global__ __launch_bounds__(256) void gn_part(const ushort* __restrict__ buf, float2* __restrict__ part) {
    int bid = blockIdx.x;
    int b = bid >> 7, ch = bid & 127;
    int t = threadIdx.x;
    int g = t & 31;
    int pxr = t >> 5;      // 0..7
    const ushort* p = buf + (b << 20) + (((ch << 5) + pxr) << 8) + (g << 3);
    float s = 0.f, s2 = 0.f;
#pragma unroll
    for (int j = 0; j < 4; ++j) {
        uint4 q = *(const uint4*)(p + j * 8 * 256);
        float v0 = bflo(q.x), v1 = bfhi(q.x), v2 = bflo(q.y), v3 = bfhi(q.y);
        float v4 = bflo(q.z), v5 = bfhi(q.z), v6 = bflo(q.w), v7 = bfhi(q.w);
        s += v0 + v1 + v2 + v3 + v4 + v5 + v6 + v7;
        s2 += v0*v0 + v1*v1 + v2*v2 + v3*v3 + v4*v4 + v5*v5 + v6*v6 + v7*v7;
    }
    __shared__ float2 red[256];
    red[t] = make_float2(s, s2);
    __syncthreads();
    if (t < 32) {
        float a = 0.f, c = 0.f;
#pragma unroll
        for (int r = 0; r < 8; ++r) { float2 v = red[t + (r << 5)]; a += v.x; c += v.y; }
        part[(bid << 5) + t] = make_float2(a, c);
    }
}

// Reduce partials -> stats[2*(b*32+g)] = {mean, rstd}
__global__ __launch_bounds__(128) void gn_finish(const float2* __restrict__ part, float* __restrict__ stats) {
    int t = threadIdx.x;     // 0..127 = b*32+g
    int b = t >> 5, g = t & 31;
    float s = 0.f, s2 = 0.f;
    for (int ch = 0; ch < 128; ++ch) {
        float2 v = part[(((b << 7) + ch) << 5) + g];
        s += v.x; s2 += v.y;
    }
    float mean = s * (1.f / 32768.f);
    float var = s2 * (1.f / 32768.f) - mean * mean;
    stats[2 * t] = mean;
    stats[2 * t + 1] = rsqrtf(var + EPSV);
}

// GN + ReLU, bf16 NHWC -> bf16 NHWC (8 ch per thread)
__global__ __launch_bounds__(256) void gn_apply_relu_bb(const ushort* __restrict__ in, const float* __restrict__ stats,
                                                        const float* __restrict__ gamma, const float* __restrict__ beta,
                                                        ushort* __restrict__ outb) {
    int q = blockIdx.x * 256 + threadIdx.x;   // 524288
    int e0 = q << 3;
    int c0 = e0 & 255;
    int b = e0 >> 20;
    int g = c0 >> 3;
    float mean = stats[((b << 5) + g) * 2];
    float rstd = stats[((b << 5) + g) * 2 + 1];
    uint4 v = *(const uint4*)(in + e0);
    float4 ga0 = ld4(&gamma[c0]), ga1 = ld4(&gamma[c0 + 4]);
    float4 be0 = ld4(&beta[c0]),  be1 = ld4(&beta[c0 + 4]);
    uint4 o;
    o.x = pk2(fmaxf((bflo(v.x) - mean) * rstd * ga0.x + be0.x, 0.f),
              fmaxf((bfhi(v.x) - mean) * rstd * ga0.y + be0.y, 0.f));
    o.y = pk2(fmaxf((bflo(v.y) - mean) * rstd * ga0.z + be0.z, 0.f),
              fmaxf((bfhi(v.y) - mean) * rstd * ga0.w + be0.w, 0.f));
    o.z = pk2(fmaxf((bflo(v.z) - mean) * rstd * ga1.x + be1.x, 0.f),
              fmaxf((bfhi(v.z) - mean) * rstd * ga1.y + be1.y, 0.f));
    o.w = pk2(fmaxf((bflo(v.w) - mean) * rstd * ga1.z + be1.z, 0.f),
              fmaxf((bfhi(v.w) - mean) * rstd * ga1.w + be1.w, 0.f));
    *(uint4*)&outb[e0] = o;
}

// NHWC bf16 -> NCHW with fused GN2 + residual + ReLU
__global__ __launch_bounds__(256) void final_bf16(const ushort* __restrict__ v2, const float* __restrict__ stats,
                                                  const float* __restrict__ gamma, const float* __restrict__ beta,
                                                  const float* __restrict__ xin, float* __restrict__ out) {
    __shared__ float lds[64][65];
    int bid = blockIdx.x;
    int cb = bid & 3, y = (bid >> 2) & 63, b = bid >> 8;
    int c0 = cb << 6;
    int tid = threadIdx.x;
#pragma unroll
    for (int i = 0; i < 4; ++i) {
        int q = tid + (i << 8);
        int x_l = q >> 4, c4 = (q & 15) << 2;
        s4_t v = *(const s4_t*)&v2[(((b << 12) + (y << 6) + x_l) << 8) + c0 + c4];
        lds[c4 + 0][x_l] = bf2f((ushort)v.x); lds[c4 + 1][x_l] = bf2f((ushort)v.y);
        lds[c4 + 2][x_l] = bf2f((ushort)v.z); lds[c4 + 3][x_l] = bf2f((ushort)v.w);
    }
    __syncthreads();
#pragma unroll
    for (int i = 0; i < 4; ++i) {
        int q = tid + (i << 8);
        int c_l = q >> 4, x4 = (q & 15) << 2;
        int c = c0 + c_l;
        int g = c >> 3;
        float mean = stats[((b << 5) + g) * 2];
        float rstd = stats[((b << 5) + g) * 2 + 1];
        float ga = gamma[c], be = beta[c];
        const float* xp = &xin[((b << 8) + c) * 4096 + (y << 6) + x4];
        float4 r = ld4(xp);
        float4 o;
        o.x = fmaxf((lds[c_l][x4 + 0] - mean) * rstd * ga + be + r.x, 0.f);
        o.y = fmaxf((lds[c_l][x4 + 1] - mean) * rstd * ga + be + r.y, 0.f);
        o.z = fmaxf((lds[c_l][x4 + 2] - mean) * rstd * ga + be + r.z, 0.f);
        o.w = fmaxf((lds[c_l][x4 + 3] - mean) * rstd * ga + be + r.w, 0.f);
        st4(&out[((b << 8) + c) * 4096 + (y << 6) + x4], o);
    }
}

extern "C" void kernel_launch(void* const* d_in, const int* in_sizes, int n_in,
                              void* d_out, int out_size, void* d_ws, size_t ws_size,
                              hipStream_t stream) {
    (void)in_sizes; (void)n_in; (void)out_size; (void)ws_size;
    const float* x      = (const float*)d_in[0];
    const float* w_off1 = (const float*)d_in[1];
    const float* b_off1 = (const float*)d_in[2];
    const float* w_off2 = (const float*)d_in[3];
    const float* b_off2 = (const float*)d_in[4];
    const float* w_def1 = (const float*)d_in[5];
    const float* w_def2 = (const float*)d_in[6];
    const float* gamma1 = (const float*)d_in[7];
    const float* beta1  = (const float*)d_in[8];
    const float* gamma2 = (const float*)d_in[9];
    const float* beta2  = (const float*)d_in[10];
    float* out = (float*)d_out;

    float* ws = (float*)d_ws;
    float*  xb_f   = ws;                      // 2,097,152 floats (8MB bf16): xb / v2b
    float*  xb2_f  = xb_f + 2097152;          // 2,097,152: xb2
    float*  wT1_f  = xb2_f + 2097152;         // 294,912
    float*  wT2_f  = wT1_f + 294912;          // 294,912
    float*  wO1_f  = wT2_f + 294912;          // 36,864
    float*  wO2_f  = wO1_f + 36864;           // 36,864
    float*  offb   = wO2_f + 36864;           // 294,912 (16384 x 18)
    float*  stats1 = offb + 294912;           // 256
    float*  stats2 = stats1 + 256;            // 256
    float*  part_f = stats2 + 256;            // 32768 (512 x 32 float2)

    ushort* xb  = (ushort*)xb_f;
    ushort* v2b = (ushort*)xb_f;
    ushort* xb2 = (ushort*)xb2_f;
    ushort* wT1 = (ushort*)wT1_f;
    ushort* wT2 = (ushort*)wT2_f;
    ushort* wO1 = (ushort*)wO1_f;
    ushort* wO2 = (ushort*)wO2_f;
    float2* part = (float2*)part_f;
    ushort* t1b = (ushort*)d_out;             // stage-1 deform out (bf16) parked in d_out

    prep_wdef_bf16<<<4608, 256, 0, stream>>>(w_def1, w_def2, wT1, wT2);
    prep_woff_bf16<<<576, 256, 0, stream>>>(w_off1, w_off2, wO1, wO2);
    transpose_to_nhwc_bf16<<<1024, 256, 0, stream>>>(x, xb);

    offconv_reg<<<1024, 64, 0, stream>>>(xb, wO1, b_off1, offb);
    deform_mfma<<<512, 256, 0, stream>>>(xb, offb, wT1, t1b);
    gn_part<<<512, 256, 0, stream>>>(t1b, part);
    gn_finish<<<1, 128, 0, stream>>>(part, stats1);
    gn_apply_relu_bb<<<2048, 256, 0, stream>>>(t1b, stats1, gamma1, beta1, xb2);

    offconv_reg<<<1024, 64, 0, stream>>>(xb2, wO2, b_off2, offb);
    deform_mfma<<<512, 256, 0, stream>>>(xb2, offb, wT2, v2b);
    gn_part<<<512, 256, 0, stream>>>(v2b, part);
    gn_finish<<<1, 128, 0, stream>>>(part, stats2);
    final_bf16<<<1024, 256, 0, stream>>>(v2b, stats2, gamma2, beta2, x, out);
}